// Round 6
// baseline (10934.164 us; speedup 1.0000x reference)
//
#include <hip/hip_runtime.h>
#include <math.h>

// JordanRNN B=128,T=2048,I=128,H=256,O=64.
// 32 WGs x 256 thr (4 waves): 8 batch-columns x 4 hidden-quarters. Weights
// register-resident fp16. NO __launch_bounds__ (its implicit waves_per_eu(1)
// was shadowing the real attribute): amdgpu_waves_per_eu(1,1) pins 1 wave/EU
// -> full unified 512-reg budget -> no spills. Per step: each wave publishes
// its own 512B h-slice (sc1), overlaps the ack with ~20 partner-independent
// pre-MFMAs (x gates K0-3, own-quarter h gates, own-quarter fc), then
// release-fence + per-wave flag; poll 12 partner wave-flags (load pre-issued);
// stage 3x2KB; finish MFMAs; gating. x staged one step ahead. 3 barriers/step.

#define TSTEPS 2048
#define ISZ 128

typedef _Float16 half8 __attribute__((ext_vector_type(8)));
typedef float f32x4 __attribute__((ext_vector_type(4)));
typedef unsigned long long u64;
#define AGENT __HIP_MEMORY_SCOPE_AGENT

__device__ __forceinline__ f32x4 mfma16(half8 a, half8 b, f32x4 c) {
  return __builtin_amdgcn_mfma_f32_16x16x32_f16(a, b, c, 0, 0, 0);
}
__device__ __forceinline__ float sigm(float x) {
  return __builtin_amdgcn_rcpf(1.f + __expf(-x));
}
__device__ __forceinline__ float tanh_fast(float x) {
  return 1.f - 2.f * __builtin_amdgcn_rcpf(1.f + __expf(2.f * x));
}

// ws: pay[2 parity][8 col][4 q][4 wv][16 rows][16 units] fp16 = 131072 B @0
//     flags u32[8 col][4 q][4 wv] = 512 B @131072   (flag=k: h(k) slice published)

__global__ __attribute__((amdgpu_flat_work_group_size(256, 256),
                          amdgpu_waves_per_eu(1, 1)))
void jordan_rnn(const float* __restrict__ xg, const float* __restrict__ w_ih,
                const float* __restrict__ w_hh, const float* __restrict__ b_ih,
                const float* __restrict__ b_hh, const float* __restrict__ fc_w,
                const float* __restrict__ fc_b, float* __restrict__ out,
                unsigned char* __restrict__ ws)
{
  const int tid  = threadIdx.x;
  const int lane = tid & 63;
  const int wv   = tid >> 6;          // wave 0..3
  const int n    = lane & 15;
  const int quad = lane >> 4;
  const int col  = blockIdx.x & 7;    // batch column; 4 quarters co-XCD
  const int q    = blockIdx.x >> 3;   // hidden quarter 0..3
  const int u0   = q * 64 + wv * 16;  // this wave's unit slice
  const int b0   = col * 16;

  unsigned char* pay = ws;
  unsigned int* flags = (unsigned int*)(ws + 131072);

  // act cols: 0..127 = x, 128..191 = y(t-1), 192..447 = h
  __shared__ _Float16 act[16][456];
  {
    unsigned int* za = (unsigned int*)&act[0][0];
    for (int i = tid; i < 3648; i += 256) za[i] = 0u;
  }

  // ---- register-resident weights (fp16 B-fragments: lane holds W[n][k32+quad*8+j])
  half8 wr[14], wz[14], win[6], whn[8], wfc[8];
  {
    const int kq = quad * 8;
    const int ur = u0 + n, uz = 256 + u0 + n, un = 512 + u0 + n;
#pragma unroll
    for (int kk = 0; kk < 6; ++kk) {            // k 0..191: w_ih (x|y)
      const float* pr = w_ih + ur * 192 + kk * 32 + kq;
      const float* pz = w_ih + uz * 192 + kk * 32 + kq;
      const float* pn = w_ih + un * 192 + kk * 32 + kq;
#pragma unroll
      for (int j = 0; j < 8; ++j) {
        wr[kk][j] = (_Float16)pr[j]; wz[kk][j] = (_Float16)pz[j]; win[kk][j] = (_Float16)pn[j];
      }
    }
#pragma unroll
    for (int kk = 0; kk < 8; ++kk) {            // k 192..447: w_hh
      const float* pr = w_hh + ur * 256 + kk * 32 + kq;
      const float* pz = w_hh + uz * 256 + kk * 32 + kq;
      const float* pn = w_hh + un * 256 + kk * 32 + kq;
#pragma unroll
      for (int j = 0; j < 8; ++j) {
        wr[6 + kk][j] = (_Float16)pr[j]; wz[6 + kk][j] = (_Float16)pz[j]; whn[kk][j] = (_Float16)pn[j];
      }
    }
#pragma unroll
    for (int kk = 0; kk < 8; ++kk) {            // fc: rows wv*16+n, all K
      const float* pf = fc_w + (wv * 16 + n) * 256 + kk * 32 + kq;
#pragma unroll
      for (int j = 0; j < 8; ++j) wfc[kk][j] = (_Float16)pf[j];
    }
  }
  const float br   = b_ih[u0 + n] + b_hh[u0 + n];
  const float bz   = b_ih[256 + u0 + n] + b_hh[256 + u0 + n];
  const float bin_ = b_ih[512 + u0 + n];
  const float bhn  = b_hh[512 + u0 + n];
  const float fcb  = fc_b[wv * 16 + n];

  float hprev[4] = {0.f, 0.f, 0.f, 0.f};

  // roles
  const int xr = tid >> 4, xc = tid & 15;       // x stage: row, 8 floats at xc*8
  const int prow = lane >> 2, pc4 = lane & 3;   // publish: 8B/lane of own 512B slice
  const int pqi = (q + 1 + (lane >> 2)) & 3;    // poll map (lane<12): partner quarter
  const int pwv = lane & 3;                     //   partner wave
  const int sblk = tid >> 6, srem = tid & 63;   // partner-quarter stage decode
  const int srow = srem >> 2, sc4 = srem & 3;
  const int ok0 = 6 + 2 * q;                    // own-quarter gate frag idx {ok0,ok0+1}
  const int fk0 = 2 * q;                        // own-quarter fc frag idx {fk0,fk0+1}

  // stage x(0) (consumed by phase A of step 1)
  {
    const float* xp = xg + (size_t)(b0 + xr) * TSTEPS * ISZ + xc * 8;
    float4 a = *(const float4*)xp, b = *(const float4*)(xp + 4);
    union { _Float16 h[8]; uint4 u; } pk;
    pk.h[0]=(_Float16)a.x; pk.h[1]=(_Float16)a.y; pk.h[2]=(_Float16)a.z; pk.h[3]=(_Float16)a.w;
    pk.h[4]=(_Float16)b.x; pk.h[5]=(_Float16)b.y; pk.h[6]=(_Float16)b.z; pk.h[7]=(_Float16)b.w;
    *(uint4*)&act[xr][xc * 8] = pk.u;
  }
  __syncthreads();

  float4 xv0, xv1;                              // holds x(t) inside step t

  for (int t = 1; t <= TSTEPS; ++t) {
    const unsigned int tgt = (unsigned int)(t - 1);
    const size_t parity = (size_t)((t - 1) & 1);

    // ---- P: publish own h(t-1) slice (512B/wave, 8B/lane, sc1 -> MALL)
    {
      u64 v = *(const u64*)&act[prow][192 + u0 + pc4 * 4];  // own wave's ds_writes (lgkm)
      u64* dst = (u64*)(pay + parity * 65536 + (size_t)col * 8192
                        + (size_t)(q * 4 + wv) * 512) + lane;
      __hip_atomic_store(dst, v, __ATOMIC_RELAXED, AGENT);
    }
    // ---- flag pre-load (latency overlaps pre-MFMAs)
    unsigned int f = (lane < 12)
        ? __hip_atomic_load(&flags[col * 16 + pqi * 4 + pwv], __ATOMIC_RELAXED, AGENT)
        : 0xFFFFFFFFu;

    // ---- A: partner-independent pre-MFMAs (overlap publish ack + flag load)
    f32x4 aR = {0,0,0,0}, aZ = {0,0,0,0}, aIN = {0,0,0,0}, aHN = {0,0,0,0};
    f32x4 accy = {0,0,0,0};
#pragma unroll
    for (int kk = 0; kk < 4; ++kk) {            // x gates
      half8 af = *(const half8*)&act[n][kk * 32 + quad * 8];
      aR = mfma16(af, wr[kk], aR);
      aZ = mfma16(af, wz[kk], aZ);
      aIN = mfma16(af, win[kk], aIN);
    }
#pragma unroll
    for (int kk = 0; kk < 2; ++kk) {            // own-quarter h gates
      half8 af = *(const half8*)&act[n][(ok0 + kk) * 32 + quad * 8];
      aR = mfma16(af, wr[ok0 + kk], aR);
      aZ = mfma16(af, wz[ok0 + kk], aZ);
      aHN = mfma16(af, whn[ok0 - 6 + kk], aHN);
    }
#pragma unroll
    for (int kk = 0; kk < 2; ++kk) {            // own-quarter fc (y(t-1) partial)
      half8 af = *(const half8*)&act[n][192 + (fk0 + kk) * 32 + quad * 8];
      accy = mfma16(af, wfc[fk0 + kk], accy);
    }

    // ---- release + per-wave flag
    __builtin_amdgcn_fence(__ATOMIC_RELEASE, "agent");
    __hip_atomic_store(&flags[col * 16 + q * 4 + wv], tgt, __ATOMIC_RELAXED, AGENT);

    // ---- prefetch x(t) (consumed at x-stage in phase B)
    {
      const size_t ts = (t < TSTEPS) ? (size_t)t : (size_t)(TSTEPS - 1);
      const float* xp = xg + ((size_t)(b0 + xr) * TSTEPS + ts) * ISZ + xc * 8;
      xv0 = *(const float4*)xp;
      xv1 = *(const float4*)(xp + 4);
    }

    // ---- poll (first check usually passes: load was pre-issued)
    while (!__all((int)(f >= tgt))) {
      f = (lane < 12)
          ? __hip_atomic_load(&flags[col * 16 + pqi * 4 + pwv], __ATOMIC_RELAXED, AGENT)
          : 0xFFFFFFFFu;
    }
    __builtin_amdgcn_fence(__ATOMIC_ACQUIRE, "agent");

    // ---- stage 3 partner h(t-1) quarters (6KB; 24B/thread)
    {
      const u64* base = (const u64*)(pay + parity * 65536 + (size_t)col * 8192);
#pragma unroll
      for (int i = 0; i < 3; ++i) {
        const int qq = (q + 1 + i) & 3;
        u64 v = base[qq * 256 + tid];
        *(u64*)&act[srow][192 + qq * 64 + sblk * 16 + sc4 * 4] = v;
      }
    }
    __syncthreads();  // S1: full h(t-1) staged

    // ---- B: partner-h gates + partner fc; y(t-1); x(t) stage
#pragma unroll
    for (int kk = 6; kk < 14; ++kk) {
      if (kk == ok0 || kk == ok0 + 1) continue;
      half8 af = *(const half8*)&act[n][kk * 32 + quad * 8];
      aR = mfma16(af, wr[kk], aR);
      aZ = mfma16(af, wz[kk], aZ);
      aHN = mfma16(af, whn[kk - 6], aHN);
    }
#pragma unroll
    for (int kk = 0; kk < 8; ++kk) {
      if (kk == fk0 || kk == fk0 + 1) continue;
      half8 af = *(const half8*)&act[n][192 + kk * 32 + quad * 8];
      accy = mfma16(af, wfc[kk], accy);
    }
    if (t > 1) {
#pragma unroll
      for (int r = 0; r < 4; ++r)
        act[quad * 4 + r][128 + wv * 16 + n] = (_Float16)tanh_fast(accy[r] + fcb);
    }
    // t==1: y(0)=0 already in act
    {
      union { _Float16 h[8]; uint4 u; } pk;
      pk.h[0]=(_Float16)xv0.x; pk.h[1]=(_Float16)xv0.y; pk.h[2]=(_Float16)xv0.z; pk.h[3]=(_Float16)xv0.w;
      pk.h[4]=(_Float16)xv1.x; pk.h[5]=(_Float16)xv1.y; pk.h[6]=(_Float16)xv1.z; pk.h[7]=(_Float16)xv1.w;
      *(uint4*)&act[xr][xc * 8] = pk.u;
    }
    __syncthreads();  // S2: y(t-1) + x(t) staged

    // ---- C: y gates K4-5, then gating
#pragma unroll
    for (int kk = 4; kk < 6; ++kk) {
      half8 af = *(const half8*)&act[n][kk * 32 + quad * 8];
      aR = mfma16(af, wr[kk], aR);
      aZ = mfma16(af, wz[kk], aZ);
      aIN = mfma16(af, win[kk], aIN);
    }
#pragma unroll
    for (int r = 0; r < 4; ++r) {
      float rg = sigm(aR[r] + br);
      float zg = sigm(aZ[r] + bz);
      float nn = tanh_fast(aIN[r] + bin_ + rg * (aHN[r] + bhn));
      float hv = (1.f - zg) * nn + zg * hprev[r];
      hprev[r] = hv;
      act[quad * 4 + r][192 + u0 + n] = (_Float16)hv;
    }
    __syncthreads();  // S3: own h(t) quarter complete in act
  }

  // ---- epilogue: publish h(T), exchange, y(T) = tanh(fc h(T) + b)
  {
    const size_t parity = (size_t)(TSTEPS & 1);
    u64 v = *(const u64*)&act[prow][192 + u0 + pc4 * 4];
    u64* dst = (u64*)(pay + parity * 65536 + (size_t)col * 8192
                      + (size_t)(q * 4 + wv) * 512) + lane;
    __hip_atomic_store(dst, v, __ATOMIC_RELAXED, AGENT);

    f32x4 accy = {0,0,0,0};
#pragma unroll
    for (int kk = 0; kk < 2; ++kk) {
      half8 af = *(const half8*)&act[n][192 + (fk0 + kk) * 32 + quad * 8];
      accy = mfma16(af, wfc[fk0 + kk], accy);
    }
    __builtin_amdgcn_fence(__ATOMIC_RELEASE, "agent");
    __hip_atomic_store(&flags[col * 16 + q * 4 + wv], (unsigned int)TSTEPS,
                       __ATOMIC_RELAXED, AGENT);
    unsigned int f;
    do {
      f = (lane < 12)
          ? __hip_atomic_load(&flags[col * 16 + pqi * 4 + pwv], __ATOMIC_RELAXED, AGENT)
          : 0xFFFFFFFFu;
    } while (!__all((int)(f >= (unsigned int)TSTEPS)));
    __builtin_amdgcn_fence(__ATOMIC_ACQUIRE, "agent");

    const u64* base = (const u64*)(pay + parity * 65536 + (size_t)col * 8192);
#pragma unroll
    for (int i = 0; i < 3; ++i) {
      const int qq = (q + 1 + i) & 3;
      u64 pv = base[qq * 256 + tid];
      *(u64*)&act[srow][192 + qq * 64 + sblk * 16 + sc4 * 4] = pv;
    }
    __syncthreads();
#pragma unroll
    for (int kk = 0; kk < 8; ++kk) {
      if (kk == fk0 || kk == fk0 + 1) continue;
      half8 af = *(const half8*)&act[n][192 + kk * 32 + quad * 8];
      accy = mfma16(af, wfc[kk], accy);
    }
    if (q == 0) {
#pragma unroll
      for (int r = 0; r < 4; ++r)
        out[(size_t)(b0 + quad * 4 + r) * 64 + wv * 16 + n] = tanh_fast(accy[r] + fcb);
    }
  }
}

extern "C" void kernel_launch(void* const* d_in, const int* in_sizes, int n_in,
                              void* d_out, int out_size, void* d_ws, size_t ws_size,
                              hipStream_t stream) {
  hipMemsetAsync(d_ws, 0, 131584, stream);  // payload (h(0)=0) + flags ("h(0) published")
  jordan_rnn<<<dim3(32), dim3(256), 0, stream>>>(
      (const float*)d_in[0], (const float*)d_in[1], (const float*)d_in[2],
      (const float*)d_in[3], (const float*)d_in[4], (const float*)d_in[5],
      (const float*)d_in[6], (float*)d_out, (unsigned char*)d_ws);
}

// Round 7
// 6198.096 us; speedup vs baseline: 1.7641x; 1.7641x over previous
//
#include <hip/hip_runtime.h>
#include <math.h>

// JordanRNN B=128,T=2048,I=128,H=256,O=64.
// 32 WGs x 256 thr (4 waves): 8 batch-columns x 4 hidden-quarters. Weights
// register-resident fp16 (unified VGPR/AGPR file; amdgpu_waves_per_eu(1,1) +
// flat_work_group_size pins 1 wave/EU -> no spills; R6-verified).
// FENCE-FREE MALL protocol (R7): all cross-WG data moves via sc1 atomic ops
// (relaxed agent scope) which bypass the non-coherent L2s and hit the MALL
// directly -- so no buffer_wbl2 / buffer_inv cache maintenance is needed.
// Producer: payload u64 relaxed stores -> s_waitcnt vmcnt(0) (MALL ack) ->
// relaxed flag store. Consumer: relaxed flag poll -> relaxed u64 payload loads.
// R6's per-wave release/acquire FENCES (8 L2-wide wbl2/inv per WG per step)
// were the 5.3us/step serializer; this removes every cache-maintenance op.

#define TSTEPS 2048
#define ISZ 128

typedef _Float16 half8 __attribute__((ext_vector_type(8)));
typedef float f32x4 __attribute__((ext_vector_type(4)));
typedef unsigned long long u64;
#define AGENT __HIP_MEMORY_SCOPE_AGENT

__device__ __forceinline__ f32x4 mfma16(half8 a, half8 b, f32x4 c) {
  return __builtin_amdgcn_mfma_f32_16x16x32_f16(a, b, c, 0, 0, 0);
}
__device__ __forceinline__ float sigm(float x) {
  return __builtin_amdgcn_rcpf(1.f + __expf(-x));
}
__device__ __forceinline__ float tanh_fast(float x) {
  return 1.f - 2.f * __builtin_amdgcn_rcpf(1.f + __expf(2.f * x));
}
// s_waitcnt vmcnt(0) only (expcnt=7, lgkmcnt=15 -> don't-care): imm = 0x0F70
#define WAIT_VM0() __builtin_amdgcn_s_waitcnt(0x0F70)

// ws: pay[2 parity][8 col][4 q][4 wv][16 rows][16 units] fp16 = 131072 B @0
//     flags u32[8 col][4 q][4 wv] = 512 B @131072   (flag=k: h(k) slice published)

__global__ __attribute__((amdgpu_flat_work_group_size(256, 256),
                          amdgpu_waves_per_eu(1, 1)))
void jordan_rnn(const float* __restrict__ xg, const float* __restrict__ w_ih,
                const float* __restrict__ w_hh, const float* __restrict__ b_ih,
                const float* __restrict__ b_hh, const float* __restrict__ fc_w,
                const float* __restrict__ fc_b, float* __restrict__ out,
                unsigned char* __restrict__ ws)
{
  const int tid  = threadIdx.x;
  const int lane = tid & 63;
  const int wv   = tid >> 6;          // wave 0..3
  const int n    = lane & 15;
  const int quad = lane >> 4;
  const int col  = blockIdx.x & 7;    // batch column; 4 quarters co-XCD
  const int q    = blockIdx.x >> 3;   // hidden quarter 0..3
  const int u0   = q * 64 + wv * 16;  // this wave's unit slice
  const int b0   = col * 16;

  unsigned char* pay = ws;
  unsigned int* flags = (unsigned int*)(ws + 131072);

  // act cols: 0..127 = x, 128..191 = y(t-1), 192..447 = h
  __shared__ _Float16 act[16][456];
  {
    unsigned int* za = (unsigned int*)&act[0][0];
    for (int i = tid; i < 3648; i += 256) za[i] = 0u;
  }

  // ---- register-resident weights (fp16 B-fragments: lane holds W[n][k32+quad*8+j])
  half8 wr[14], wz[14], win[6], whn[8], wfc[8];
  {
    const int kq = quad * 8;
    const int ur = u0 + n, uz = 256 + u0 + n, un = 512 + u0 + n;
#pragma unroll
    for (int kk = 0; kk < 6; ++kk) {            // k 0..191: w_ih (x|y)
      const float* pr = w_ih + ur * 192 + kk * 32 + kq;
      const float* pz = w_ih + uz * 192 + kk * 32 + kq;
      const float* pn = w_ih + un * 192 + kk * 32 + kq;
#pragma unroll
      for (int j = 0; j < 8; ++j) {
        wr[kk][j] = (_Float16)pr[j]; wz[kk][j] = (_Float16)pz[j]; win[kk][j] = (_Float16)pn[j];
      }
    }
#pragma unroll
    for (int kk = 0; kk < 8; ++kk) {            // k 192..447: w_hh
      const float* pr = w_hh + ur * 256 + kk * 32 + kq;
      const float* pz = w_hh + uz * 256 + kk * 32 + kq;
      const float* pn = w_hh + un * 256 + kk * 32 + kq;
#pragma unroll
      for (int j = 0; j < 8; ++j) {
        wr[6 + kk][j] = (_Float16)pr[j]; wz[6 + kk][j] = (_Float16)pz[j]; whn[kk][j] = (_Float16)pn[j];
      }
    }
#pragma unroll
    for (int kk = 0; kk < 8; ++kk) {            // fc: rows wv*16+n, all K
      const float* pf = fc_w + (wv * 16 + n) * 256 + kk * 32 + kq;
#pragma unroll
      for (int j = 0; j < 8; ++j) wfc[kk][j] = (_Float16)pf[j];
    }
  }
  const float br   = b_ih[u0 + n] + b_hh[u0 + n];
  const float bz   = b_ih[256 + u0 + n] + b_hh[256 + u0 + n];
  const float bin_ = b_ih[512 + u0 + n];
  const float bhn  = b_hh[512 + u0 + n];
  const float fcb  = fc_b[wv * 16 + n];

  float hprev[4] = {0.f, 0.f, 0.f, 0.f};

  // roles
  const int xr = tid >> 4, xc = tid & 15;       // x stage: row, 8 floats at xc*8
  const int prow = lane >> 2, pc4 = lane & 3;   // publish: 8B/lane of own 512B slice
  const int pqi = (q + 1 + (lane >> 2)) & 3;    // poll map (lane<12): partner quarter
  const int pwv = lane & 3;                     //   partner wave
  const int sblk = tid >> 6, srem = tid & 63;   // partner-quarter stage decode
  const int srow = srem >> 2, sc4 = srem & 3;
  const int ok0 = 6 + 2 * q;                    // own-quarter gate frag idx {ok0,ok0+1}
  const int fk0 = 2 * q;                        // own-quarter fc frag idx {fk0,fk0+1}

  // stage x(0) (consumed by phase A of step 1)
  {
    const float* xp = xg + (size_t)(b0 + xr) * TSTEPS * ISZ + xc * 8;
    float4 a = *(const float4*)xp, b = *(const float4*)(xp + 4);
    union { _Float16 h[8]; uint4 u; } pk;
    pk.h[0]=(_Float16)a.x; pk.h[1]=(_Float16)a.y; pk.h[2]=(_Float16)a.z; pk.h[3]=(_Float16)a.w;
    pk.h[4]=(_Float16)b.x; pk.h[5]=(_Float16)b.y; pk.h[6]=(_Float16)b.z; pk.h[7]=(_Float16)b.w;
    *(uint4*)&act[xr][xc * 8] = pk.u;
  }
  __syncthreads();

  float4 xv0, xv1;                              // holds x(t) inside step t

  for (int t = 1; t <= TSTEPS; ++t) {
    const unsigned int tgt = (unsigned int)(t - 1);
    const size_t parity = (size_t)((t - 1) & 1);

    // ---- P: publish own h(t-1) slice (512B/wave, 8B/lane, sc1 -> MALL)
    {
      u64 v = *(const u64*)&act[prow][192 + u0 + pc4 * 4];  // own wave's ds_writes (lgkm)
      u64* dst = (u64*)(pay + parity * 65536 + (size_t)col * 8192
                        + (size_t)(q * 4 + wv) * 512) + lane;
      __hip_atomic_store(dst, v, __ATOMIC_RELAXED, AGENT);
    }
    // ---- flag pre-load (latency overlaps pre-MFMAs)
    unsigned int f = (lane < 12)
        ? __hip_atomic_load(&flags[col * 16 + pqi * 4 + pwv], __ATOMIC_RELAXED, AGENT)
        : 0xFFFFFFFFu;

    // ---- A: partner-independent pre-MFMAs (overlap publish ack + flag load)
    f32x4 aR = {0,0,0,0}, aZ = {0,0,0,0}, aIN = {0,0,0,0}, aHN = {0,0,0,0};
    f32x4 accy = {0,0,0,0};
#pragma unroll
    for (int kk = 0; kk < 4; ++kk) {            // x gates
      half8 af = *(const half8*)&act[n][kk * 32 + quad * 8];
      aR = mfma16(af, wr[kk], aR);
      aZ = mfma16(af, wz[kk], aZ);
      aIN = mfma16(af, win[kk], aIN);
    }
#pragma unroll
    for (int kk = 0; kk < 2; ++kk) {            // own-quarter h gates
      half8 af = *(const half8*)&act[n][(ok0 + kk) * 32 + quad * 8];
      aR = mfma16(af, wr[ok0 + kk], aR);
      aZ = mfma16(af, wz[ok0 + kk], aZ);
      aHN = mfma16(af, whn[ok0 - 6 + kk], aHN);
    }
#pragma unroll
    for (int kk = 0; kk < 2; ++kk) {            // own-quarter fc (y(t-1) partial)
      half8 af = *(const half8*)&act[n][192 + (fk0 + kk) * 32 + quad * 8];
      accy = mfma16(af, wfc[fk0 + kk], accy);
    }

    // ---- ordered flag: payload stores ACKed at MALL, then flag (no wbl2!)
    WAIT_VM0();
    __hip_atomic_store(&flags[col * 16 + q * 4 + wv], tgt, __ATOMIC_RELAXED, AGENT);

    // ---- prefetch x(t) (consumed at x-stage in phase B; L2 stays warm now)
    {
      const size_t ts = (t < TSTEPS) ? (size_t)t : (size_t)(TSTEPS - 1);
      const float* xp = xg + ((size_t)(b0 + xr) * TSTEPS + ts) * ISZ + xc * 8;
      xv0 = *(const float4*)xp;
      xv1 = *(const float4*)(xp + 4);
    }

    // ---- poll (first check usually passes: load was pre-issued)
    while (!__all((int)(f >= tgt))) {
      f = (lane < 12)
          ? __hip_atomic_load(&flags[col * 16 + pqi * 4 + pwv], __ATOMIC_RELAXED, AGENT)
          : 0xFFFFFFFFu;
    }
    // NO acquire fence: payload is read with sc1 atomic loads (direct MALL)

    // ---- stage 3 partner h(t-1) quarters (6KB; 24B/thread, relaxed u64 loads)
    {
      const u64* base = (const u64*)(pay + parity * 65536 + (size_t)col * 8192);
#pragma unroll
      for (int i = 0; i < 3; ++i) {
        const int qq = (q + 1 + i) & 3;
        u64 v = __hip_atomic_load(base + qq * 256 + tid, __ATOMIC_RELAXED, AGENT);
        *(u64*)&act[srow][192 + qq * 64 + sblk * 16 + sc4 * 4] = v;
      }
    }
    __syncthreads();  // S1: full h(t-1) staged

    // ---- B: partner-h gates + partner fc; y(t-1); x(t) stage
#pragma unroll
    for (int kk = 6; kk < 14; ++kk) {
      if (kk == ok0 || kk == ok0 + 1) continue;
      half8 af = *(const half8*)&act[n][kk * 32 + quad * 8];
      aR = mfma16(af, wr[kk], aR);
      aZ = mfma16(af, wz[kk], aZ);
      aHN = mfma16(af, whn[kk - 6], aHN);
    }
#pragma unroll
    for (int kk = 0; kk < 8; ++kk) {
      if (kk == fk0 || kk == fk0 + 1) continue;
      half8 af = *(const half8*)&act[n][192 + kk * 32 + quad * 8];
      accy = mfma16(af, wfc[kk], accy);
    }
    if (t > 1) {
#pragma unroll
      for (int r = 0; r < 4; ++r)
        act[quad * 4 + r][128 + wv * 16 + n] = (_Float16)tanh_fast(accy[r] + fcb);
    }
    // t==1: y(0)=0 already in act
    {
      union { _Float16 h[8]; uint4 u; } pk;
      pk.h[0]=(_Float16)xv0.x; pk.h[1]=(_Float16)xv0.y; pk.h[2]=(_Float16)xv0.z; pk.h[3]=(_Float16)xv0.w;
      pk.h[4]=(_Float16)xv1.x; pk.h[5]=(_Float16)xv1.y; pk.h[6]=(_Float16)xv1.z; pk.h[7]=(_Float16)xv1.w;
      *(uint4*)&act[xr][xc * 8] = pk.u;
    }
    __syncthreads();  // S2: y(t-1) + x(t) staged

    // ---- C: y gates K4-5, then gating
#pragma unroll
    for (int kk = 4; kk < 6; ++kk) {
      half8 af = *(const half8*)&act[n][kk * 32 + quad * 8];
      aR = mfma16(af, wr[kk], aR);
      aZ = mfma16(af, wz[kk], aZ);
      aIN = mfma16(af, win[kk], aIN);
    }
#pragma unroll
    for (int r = 0; r < 4; ++r) {
      float rg = sigm(aR[r] + br);
      float zg = sigm(aZ[r] + bz);
      float nn = tanh_fast(aIN[r] + bin_ + rg * (aHN[r] + bhn));
      float hv = (1.f - zg) * nn + zg * hprev[r];
      hprev[r] = hv;
      act[quad * 4 + r][192 + u0 + n] = (_Float16)hv;
    }
    __syncthreads();  // S3: own h(t) quarter complete in act
  }

  // ---- epilogue: publish h(T), exchange, y(T) = tanh(fc h(T) + b)
  {
    const size_t parity = (size_t)(TSTEPS & 1);
    u64 v = *(const u64*)&act[prow][192 + u0 + pc4 * 4];
    u64* dst = (u64*)(pay + parity * 65536 + (size_t)col * 8192
                      + (size_t)(q * 4 + wv) * 512) + lane;
    __hip_atomic_store(dst, v, __ATOMIC_RELAXED, AGENT);

    f32x4 accy = {0,0,0,0};
#pragma unroll
    for (int kk = 0; kk < 2; ++kk) {
      half8 af = *(const half8*)&act[n][192 + (fk0 + kk) * 32 + quad * 8];
      accy = mfma16(af, wfc[fk0 + kk], accy);
    }
    WAIT_VM0();
    __hip_atomic_store(&flags[col * 16 + q * 4 + wv], (unsigned int)TSTEPS,
                       __ATOMIC_RELAXED, AGENT);
    unsigned int f;
    do {
      f = (lane < 12)
          ? __hip_atomic_load(&flags[col * 16 + pqi * 4 + pwv], __ATOMIC_RELAXED, AGENT)
          : 0xFFFFFFFFu;
    } while (!__all((int)(f >= (unsigned int)TSTEPS)));

    const u64* base = (const u64*)(pay + parity * 65536 + (size_t)col * 8192);
#pragma unroll
    for (int i = 0; i < 3; ++i) {
      const int qq = (q + 1 + i) & 3;
      u64 pv = __hip_atomic_load(base + qq * 256 + tid, __ATOMIC_RELAXED, AGENT);
      *(u64*)&act[srow][192 + qq * 64 + sblk * 16 + sc4 * 4] = pv;
    }
    __syncthreads();
#pragma unroll
    for (int kk = 0; kk < 8; ++kk) {
      if (kk == fk0 || kk == fk0 + 1) continue;
      half8 af = *(const half8*)&act[n][192 + kk * 32 + quad * 8];
      accy = mfma16(af, wfc[kk], accy);
    }
    if (q == 0) {
#pragma unroll
      for (int r = 0; r < 4; ++r)
        out[(size_t)(b0 + quad * 4 + r) * 64 + wv * 16 + n] = tanh_fast(accy[r] + fcb);
    }
  }
}

extern "C" void kernel_launch(void* const* d_in, const int* in_sizes, int n_in,
                              void* d_out, int out_size, void* d_ws, size_t ws_size,
                              hipStream_t stream) {
  hipMemsetAsync(d_ws, 0, 131584, stream);  // payload (h(0)=0) + flags ("h(0) published")
  jordan_rnn<<<dim3(32), dim3(256), 0, stream>>>(
      (const float*)d_in[0], (const float*)d_in[1], (const float*)d_in[2],
      (const float*)d_in[3], (const float*)d_in[4], (const float*)d_in[5],
      (const float*)d_in[6], (float*)d_out, (unsigned char*)d_ws);
}